// Round 11
// baseline (260.437 us; speedup 1.0000x reference)
//
#include <hip/hip_runtime.h>

#define NN 100000
#define NE 800000
#define NPB 512   // k_pool blocks
#define SRCMASK 0x01FFFFFF

typedef short bf16x8 __attribute__((ext_vector_type(8)));
typedef float f32x4 __attribute__((ext_vector_type(4)));

__device__ __forceinline__ float wave_reduce_sum(float v) {
    #pragma unroll
    for (int o = 32; o > 0; o >>= 1) v += __shfl_down(v, o, 64);
    return v; // valid in lane 0
}

__device__ __forceinline__ unsigned short f2bf(float f) {
    unsigned u = __float_as_uint(f);
    unsigned r = (u + 0x7FFFu + ((u >> 16) & 1u)) >> 16;
    return (unsigned short)r;
}
__device__ __forceinline__ float bf2f(unsigned short b) {
    return __uint_as_float(((unsigned)b) << 16);
}
__device__ __forceinline__ float bflo(unsigned u) {   // low bf16 of u32
    return __uint_as_float(u << 16);
}
__device__ __forceinline__ float bfhi(unsigned u) {   // high bf16 of u32
    return __uint_as_float(u & 0xFFFF0000u);
}

// cb layout (floats): [0..27] vs1(k*4+h)  [28..55] vd1  [56..59] c1[h]  [60] c2
__global__ void k_pre(const float* __restrict__ W1, const float* __restrict__ as1,
                      const float* __restrict__ ad1,
                      const float* __restrict__ We1, const float* __restrict__ ae1,
                      const float* __restrict__ We2, const float* __restrict__ ae2,
                      const float* __restrict__ W2,
                      float* __restrict__ cb, unsigned short* __restrict__ W2fr) {
    int t = threadIdx.x;
    if (blockIdx.x == 0) {
        if (t < 28) {
            int k = t >> 2, h = t & 3;
            float s = 0.f, d = 0.f;
            for (int c = 0; c < 64; ++c) {
                float w = W1[k * 256 + h * 64 + c];
                s += w * as1[h * 64 + c];
                d += w * ad1[h * 64 + c];
            }
            cb[t] = s; cb[28 + t] = d;
        } else if (t < 32) {
            int h = t - 28;
            float s = 0.f;
            for (int c = 0; c < 64; ++c) s += We1[h * 64 + c] * ae1[h * 64 + c];
            cb[56 + h] = s;
        } else if (t == 32) {
            float s = 0.f;
            for (int c = 0; c < 64; ++c) s += We2[c] * ae2[c];
            cb[60] = s;
        }
    } else {
        int o = (blockIdx.x - 1) * 256 + t;        // 0..16383
        int i = o & 7, l = (o >> 3) & 63, ct = (o >> 9) & 3, ks = o >> 11;
        int k = ks * 32 + ((l >> 4) * 8) + i;
        int col = ct * 16 + (l & 15);
        W2fr[o] = f2bf(W2[k * 64 + col]);
    }
}

// per-node: conv1 attention coefficients + packed bf16 x-record; fused dst histogram
__global__ void k_node1h(const float* __restrict__ x, const float* __restrict__ cb,
                         const int* __restrict__ dst,
                         float* __restrict__ a_src1, float* __restrict__ a_dst1,
                         uint4* __restrict__ xpack, int* __restrict__ hist) {
    int n = blockIdx.x * 256 + threadIdx.x;
    if (n >= NN) return;
    float xv[7];
    #pragma unroll
    for (int k = 0; k < 7; ++k) xv[k] = x[n * 7 + k];
    float s[4] = {0.f, 0.f, 0.f, 0.f}, d[4] = {0.f, 0.f, 0.f, 0.f};
    #pragma unroll
    for (int k = 0; k < 7; ++k)
        #pragma unroll
        for (int h = 0; h < 4; ++h) {
            s[h] += xv[k] * cb[k * 4 + h];
            d[h] += xv[k] * cb[28 + k * 4 + h];
        }
    *(float4*)(a_src1 + n * 4) = make_float4(s[0], s[1], s[2], s[3]);
    *(float4*)(a_dst1 + n * 4) = make_float4(d[0], d[1], d[2], d[3]);
    unsigned p0 = (unsigned)f2bf(xv[0]) | ((unsigned)f2bf(xv[1]) << 16);
    unsigned p1 = (unsigned)f2bf(xv[2]) | ((unsigned)f2bf(xv[3]) << 16);
    unsigned p2 = (unsigned)f2bf(xv[4]) | ((unsigned)f2bf(xv[5]) << 16);
    unsigned p3 = (unsigned)f2bf(xv[6]) | ((unsigned)f2bf(1.f) << 16);
    xpack[n] = make_uint4(p0, p1, p2, p3);
    // histogram: edges [n*8, n*8+8)
    int e0 = n * 8;
    int4 d0 = *(const int4*)(dst + e0);
    int4 d1 = *(const int4*)(dst + e0 + 4);
    atomicAdd(&hist[d0.x], 1); atomicAdd(&hist[d0.y], 1);
    atomicAdd(&hist[d0.z], 1); atomicAdd(&hist[d0.w], 1);
    atomicAdd(&hist[d1.x], 1); atomicAdd(&hist[d1.y], 1);
    atomicAdd(&hist[d1.z], 1); atomicAdd(&hist[d1.w], 1);
}

// --- 3-phase parallel exclusive scan over hist[NN] -> offs[NN+1], cursor[NN] ---
__global__ __launch_bounds__(1024) void k_scanA(const int* __restrict__ hist,
                                                int* __restrict__ bsum) {
    __shared__ int ws[16];
    int i = blockIdx.x * 1024 + threadIdx.x;
    int lane = threadIdx.x & 63, wid = threadIdx.x >> 6;
    int v = (i < NN) ? hist[i] : 0;
    #pragma unroll
    for (int o = 32; o; o >>= 1) v += __shfl_down(v, o, 64);
    if (lane == 0) ws[wid] = v;
    __syncthreads();
    if (wid == 0) {
        int u = (lane < 16) ? ws[lane] : 0;
        #pragma unroll
        for (int o = 8; o; o >>= 1) u += __shfl_down(u, o, 64);
        if (lane == 0) bsum[blockIdx.x] = u;
    }
}

__global__ void k_scanB(const int* __restrict__ bsum, int* __restrict__ bexcl) {
    __shared__ int w0tot;
    int t = threadIdx.x, lane = t & 63, wid = t >> 6;
    int v = (t < 98) ? bsum[t] : 0;
    int s = v;
    #pragma unroll
    for (int d = 1; d < 64; d <<= 1) { int u = __shfl_up(s, d, 64); if (lane >= d) s += u; }
    if (t == 63) w0tot = s;
    __syncthreads();
    if (wid == 1) s += w0tot;
    if (t < 98) bexcl[t] = s - v;
}

__global__ __launch_bounds__(1024) void k_scanC(const int* __restrict__ hist,
                                                const int* __restrict__ bexcl,
                                                int* __restrict__ offs,
                                                int* __restrict__ cursor) {
    __shared__ int ws[16];
    int b = blockIdx.x;
    int i = b * 1024 + threadIdx.x;
    int lane = threadIdx.x & 63, wid = threadIdx.x >> 6;
    int v = (i < NN) ? hist[i] : 0;
    int s = v;
    #pragma unroll
    for (int d = 1; d < 64; d <<= 1) { int u = __shfl_up(s, d, 64); if (lane >= d) s += u; }
    if (lane == 63) ws[wid] = s;
    __syncthreads();
    if (wid == 0) {
        int u2 = (lane < 16) ? ws[lane] : 0;
        #pragma unroll
        for (int d = 1; d < 16; d <<= 1) { int uu = __shfl_up(u2, d, 64); if (lane >= d) u2 += uu; }
        if (lane < 16) ws[lane] = u2;
    }
    __syncthreads();
    int incl = s + (wid ? ws[wid - 1] : 0) + bexcl[b];
    if (i < NN) { offs[i + 1] = incl; cursor[i] = incl - v; }
    if (i == 0) offs[0] = 0;
}

// scatter + conv1 edge weights: es2[pos] = {w01, w23 (bf16x4), src|(dst&31)<<25, ea}
__global__ void k_scatter(const int* __restrict__ src, const int* __restrict__ dst,
                          const float* __restrict__ ea,
                          const float* __restrict__ a_src1, const float* __restrict__ a_dst1,
                          const float* __restrict__ cb,
                          int* __restrict__ cursor, int4* __restrict__ es2) {
    int e = blockIdx.x * 256 + threadIdx.x;
    if (e >= NE) return;
    int s = src[e], d = dst[e];
    float eav = ea[e];
    int pos = atomicAdd(&cursor[d], 1);
    float4 as_ = *(const float4*)(a_src1 + s * 4);
    float4 ad_ = *(const float4*)(a_dst1 + d * 4);
    float lg0 = as_.x + ad_.x + eav * cb[56];
    float lg1 = as_.y + ad_.y + eav * cb[57];
    float lg2 = as_.z + ad_.z + eav * cb[58];
    float lg3 = as_.w + ad_.w + eav * cb[59];
    lg0 = lg0 >= 0.f ? lg0 : 0.2f * lg0;
    lg1 = lg1 >= 0.f ? lg1 : 0.2f * lg1;
    lg2 = lg2 >= 0.f ? lg2 : 0.2f * lg2;
    lg3 = lg3 >= 0.f ? lg3 : 0.2f * lg3;
    unsigned w01 = (unsigned)f2bf(__expf(lg0)) | ((unsigned)f2bf(__expf(lg1)) << 16);
    unsigned w23 = (unsigned)f2bf(__expf(lg2)) | ((unsigned)f2bf(__expf(lg3)) << 16);
    es2[pos] = make_int4((int)w01, (int)w23, s | ((d & 31) << 25), __float_as_int(eav));
}

// fused conv1: packed-LDS two-phase segmented reduce -> h -> MFMA (xh2 + a_src2/a_dst2)
//              + einf epilogue for flat conv2 normalization
__global__ __launch_bounds__(256, 7) void k_conv1red(
    const uint4* __restrict__ xpack, const float* __restrict__ W1, const float* __restrict__ b1,
    const int* __restrict__ offs, const int4* __restrict__ es2,
    const float* __restrict__ as2, const float* __restrict__ ad2,
    const unsigned short* __restrict__ W2fr, const int* __restrict__ assign,
    unsigned short* __restrict__ xh2b, float* __restrict__ a_src2, float* __restrict__ a_dst2,
    int2* __restrict__ einf) {
    // overlay: xs/wsx (phases 1-2) share storage with hs (finish/MFMA phases)
    __shared__ __attribute__((aligned(16))) unsigned char smem[16896];
    uint4* xs = (uint4*)smem;                                   // [256] 4096 B
    uint2* wsx = (uint2*)(smem + 4096);                         // [256] 2048 B
    typedef unsigned short hsrow[264];
    hsrow* hs = (hsrow*)smem;                                   // [32][264] 16896 B
    __shared__ int soffs[33];
    __shared__ int asgL[32];
    __shared__ float sacc[32], dacc[32];
    __shared__ float ms[32][33];
    int t = threadIdx.x, lane = t & 63, wid = t >> 6;
    int n0 = blockIdx.x * 32;
    if (t <= 32) soffs[t] = offs[n0 + t];
    if (t < 32) { sacc[t] = 0.f; dacc[t] = 0.f; asgL[t] = assign[n0 + t]; }
    float w1r[7][4], b1r[4];
    #pragma unroll
    for (int k = 0; k < 7; ++k)
        #pragma unroll
        for (int h = 0; h < 4; ++h) w1r[k][h] = W1[k * 256 + h * 64 + lane];
    #pragma unroll
    for (int h = 0; h < 4; ++h) b1r[h] = b1[h * 64 + lane];
    __syncthreads();
    int E0 = soffs[0], E1 = soffs[32];
    int g = t >> 3, q = t & 7;
    int go0 = soffs[g], go1 = soffs[g + 1];
    int qh = q >> 1;
    int xsl = (q & 1) ? 0 : 16;    // shift to put selected bf16 in high half
    float mh0 = 0.f, mh1 = 0.f, mh2 = 0.f, mh3 = 0.f;
    for (int C0 = E0; C0 < E1; C0 += 256) {
        int C1 = min(C0 + 256, E1);
        int j = C0 + t;
        if (j < C1) {
            int4 e4 = es2[j];
            xs[t] = xpack[e4.z & SRCMASK];
            wsx[t] = make_uint2((unsigned)e4.x, (unsigned)e4.y);
        }
        __syncthreads();
        int lo = max(go0, C0) - C0, hi = min(go1, C1) - C0;
        for (int jj = lo; jj < hi; ++jj) {
            unsigned xu = ((const unsigned*)&xs[jj])[qh];
            float xv = __uint_as_float((xu << xsl) & 0xFFFF0000u);
            uint2 wv = wsx[jj];
            mh0 = fmaf(bflo(wv.x), xv, mh0);
            mh1 = fmaf(bfhi(wv.x), xv, mh1);
            mh2 = fmaf(bflo(wv.y), xv, mh2);
            mh3 = fmaf(bfhi(wv.y), xv, mh3);
        }
        __syncthreads();
    }
    ms[g][0 * 8 + q] = mh0; ms[g][1 * 8 + q] = mh1;
    ms[g][2 * 8 + q] = mh2; ms[g][3 * 8 + q] = mh3;
    __syncthreads();          // xs/wsx dead from here; hs may now overwrite
    // finish: 8 nodes per wave, lane = channel
    for (int gi = wid * 8; gi < wid * 8 + 8; ++gi) {
        bool has = soffs[gi + 1] > soffs[gi];
        #pragma unroll
        for (int h = 0; h < 4; ++h) {
            float rz = __builtin_amdgcn_rcpf(ms[gi][h * 8 + 7]);
            float a = 0.f;
            #pragma unroll
            for (int k = 0; k < 7; ++k) a = fmaf(ms[gi][h * 8 + k], w1r[k][h], a);
            float mm = (has ? a * rz : 0.f) + b1r[h];
            float hv = mm > 0.f ? mm : (__expf(mm) - 1.f);
            hs[gi][h * 64 + lane] = f2bf(hv);
        }
    }
    __syncthreads();
    // MFMA: 2 node-tiles x 4 col-tiles; epilogue computes a_src2/a_dst2 from acc
    int row = lane & 15, kg = lane >> 4;
    #pragma unroll
    for (int u = wid; u < 8; u += 4) {
        int nt = u & 1, ct = u >> 1;
        f32x4 acc = {0.f, 0.f, 0.f, 0.f};
        #pragma unroll
        for (int ks = 0; ks < 8; ++ks) {
            bf16x8 av = *(const bf16x8*)&hs[nt * 16 + row][ks * 32 + kg * 8];
            bf16x8 bv = *(const bf16x8*)(W2fr + (((ks * 4 + ct) * 64) + lane) * 8);
            acc = __builtin_amdgcn_mfma_f32_16x16x32_bf16(av, bv, acc, 0, 0, 0);
        }
        float as2v = as2[ct * 16 + row];
        float ad2v = ad2[ct * 16 + row];
        #pragma unroll
        for (int i = 0; i < 4; ++i) {
            xh2b[(n0 + nt * 16 + kg * 4 + i) * 64 + ct * 16 + row] = f2bf(acc[i]);
            float ps = acc[i] * as2v;
            float pd = acc[i] * ad2v;
            #pragma unroll
            for (int o = 1; o < 16; o <<= 1) {
                ps += __shfl_xor(ps, o, 64);
                pd += __shfl_xor(pd, o, 64);
            }
            if (row == 0) {
                atomicAdd(&sacc[nt * 16 + kg * 4 + i], ps);
                atomicAdd(&dacc[nt * 16 + kg * 4 + i], pd);
            }
        }
    }
    __syncthreads();
    if (t < 32) {
        a_src2[n0 + t] = sacc[t];
        a_dst2[n0 + t] = dacc[t];
    }
    // einf epilogue: per-edge {src | cluster(dst)<<25, dst} for flat conv2 kernels
    for (int j = E0 + t; j < E1; j += 256) {
        int z_ = es2[j].z;
        int d5 = (z_ >> 25) & 31;
        einf[j] = make_int2((z_ & SRCMASK) | (asgL[d5] << 25), n0 + d5);
    }
}

// conv2 pass A (flat edge-parallel): ew = exp(leaky(logit)); z1[dst] += ew
__global__ void k_zA(const int4* __restrict__ es2, const int2* __restrict__ einf,
                     const float* __restrict__ a_src2, const float* __restrict__ a_dst2,
                     const float* __restrict__ cb,
                     float* __restrict__ ewv, float* __restrict__ z1) {
    int j = blockIdx.x * 256 + threadIdx.x;
    if (j >= NE) return;
    int4 e4 = es2[j];
    int2 ei = einf[j];
    int sx = ei.x & SRCMASK;
    int n = ei.y;
    float lg = a_src2[sx] + a_dst2[n] + __int_as_float(e4.w) * cb[60];
    lg = lg >= 0.f ? lg : 0.2f * lg;
    float ew = __expf(lg);
    ewv[j] = ew;
    atomicAdd(&z1[n], ew);
}

// conv2 pass B (flat edge-parallel): cs[src][c] += ew / z1[dst]
__global__ void k_zB(const int2* __restrict__ einf, const float* __restrict__ ewv,
                     const float* __restrict__ z1, float* __restrict__ cs) {
    int j = blockIdx.x * 256 + threadIdx.x;
    if (j >= NE) return;
    int2 ei = einf[j];
    float rz = __builtin_amdgcn_rcpf(z1[ei.y]);
    atomicAdd(&cs[(ei.x & SRCMASK) * 4 + (ei.x >> 25)], ewv[j] * rz);
}

// pooling as tiny GEMM: 8 lanes/node, 16B loads, register accumulators, direct gacc atomics
__global__ __launch_bounds__(256) void k_pool(
    const unsigned short* __restrict__ xh2b, const float* __restrict__ cs,
    const int* __restrict__ assign, const float* __restrict__ x,
    float* __restrict__ gacc) {
    __shared__ float csum[264];
    int t = threadIdx.x;
    int q = t & 7, slot = t >> 3;             // 32 node-slots per block
    float a0[8], a1[8], a2[8], a3[8];
    #pragma unroll
    for (int j = 0; j < 8; ++j) { a0[j] = 0.f; a1[j] = 0.f; a2[j] = 0.f; a3[j] = 0.f; }
    float cnt0 = 0.f, cnt1 = 0.f, cnt2 = 0.f, cnt3 = 0.f;
    float cf0 = 0.f, cf1 = 0.f, cf2 = 0.f, cf3 = 0.f;
    for (int n = blockIdx.x * 32 + slot; n < NN; n += NPB * 32) {
        uint4 u = *(const uint4*)(xh2b + n * 64 + q * 8);
        float4 c4 = *(const float4*)(cs + n * 4);
        float xv[8];
        xv[0] = bf2f((unsigned short)u.x); xv[1] = bf2f((unsigned short)(u.x >> 16));
        xv[2] = bf2f((unsigned short)u.y); xv[3] = bf2f((unsigned short)(u.y >> 16));
        xv[4] = bf2f((unsigned short)u.z); xv[5] = bf2f((unsigned short)(u.z >> 16));
        xv[6] = bf2f((unsigned short)u.w); xv[7] = bf2f((unsigned short)(u.w >> 16));
        #pragma unroll
        for (int j = 0; j < 8; ++j) {
            a0[j] = fmaf(c4.x, xv[j], a0[j]);
            a1[j] = fmaf(c4.y, xv[j], a1[j]);
            a2[j] = fmaf(c4.z, xv[j], a2[j]);
            a3[j] = fmaf(c4.w, xv[j], a3[j]);
        }
        if (q == 0) {
            int a = assign[n];
            float xf = x[n * 7 + 6];
            cnt0 += (a == 0) ? 1.f : 0.f;  cf0 += (a == 0) ? xf : 0.f;
            cnt1 += (a == 1) ? 1.f : 0.f;  cf1 += (a == 1) ? xf : 0.f;
            cnt2 += (a == 2) ? 1.f : 0.f;  cf2 += (a == 2) ? xf : 0.f;
            cnt3 += (a == 3) ? 1.f : 0.f;  cf3 += (a == 3) ? xf : 0.f;
        }
    }
    for (int i = t; i < 264; i += 256) csum[i] = 0.f;
    __syncthreads();
    int base = q * 8;
    #pragma unroll
    for (int j = 0; j < 8; ++j) {
        atomicAdd(&csum[0 * 64 + base + j], a0[j]);
        atomicAdd(&csum[1 * 64 + base + j], a1[j]);
        atomicAdd(&csum[2 * 64 + base + j], a2[j]);
        atomicAdd(&csum[3 * 64 + base + j], a3[j]);
    }
    if (q == 0) {
        atomicAdd(&csum[256], cnt0); atomicAdd(&csum[257], cnt1);
        atomicAdd(&csum[258], cnt2); atomicAdd(&csum[259], cnt3);
        atomicAdd(&csum[260], cf0);  atomicAdd(&csum[261], cf1);
        atomicAdd(&csum[262], cf2);  atomicAdd(&csum[263], cf3);
    }
    __syncthreads();
    for (int i = t; i < 264; i += 256) atomicAdd(&gacc[i], csum[i]);
}

// final head (256 threads): cluster means (+cnt*b2), actor MLP + softmax, critic MLP
__global__ __launch_bounds__(256) void k_head(
    const float* __restrict__ gacc, const float* __restrict__ b2,
    const float* __restrict__ A1, const float* __restrict__ ba1,
    const float* __restrict__ A2, const float* __restrict__ ba2,
    const float* __restrict__ C1, const float* __restrict__ bc1,
    const float* __restrict__ C2, const float* __restrict__ bc2,
    float* __restrict__ out) {
    __shared__ float zc[4][64];
    __shared__ float cfs[4];
    __shared__ float logits[4];
    __shared__ float vpart[4][64];
    int t = threadIdx.x;
    int j = t & 63, wv = t >> 6;   // wave wv handles cluster wv
    float cnt = gacc[256 + wv];
    float den = fmaxf(cnt, 1.f);
    zc[wv][j] = (cnt > 0.f) ? (gacc[wv * 64 + j] + cnt * b2[j]) / den : 0.f;
    if (t < 4) {
        float cc = gacc[256 + t];
        cfs[t] = (cc > 0.f) ? gacc[260 + t] / fmaxf(cc, 1.f) : 0.f;
    }
    __syncthreads();
    // actor: cluster wv
    float tv = ba1[j];
    for (int k = 0; k < 64; ++k) tv = fmaf(zc[wv][k], A1[k * 64 + j], tv);
    tv = fmaf(cfs[wv], A1[64 * 64 + j], tv);
    tv = fmaxf(tv, 0.f);
    float sred = wave_reduce_sum(tv * A2[j]);
    if (j == 0) logits[wv] = sred + ba2[0];
    // critic partials: wave wv covers k in [wv*64, (wv+1)*64)
    float vj = (wv == 0) ? bc1[j] : 0.f;
    for (int kk = 0; kk < 64; ++kk) vj = fmaf(zc[wv][kk], C1[(wv * 64 + kk) * 64 + j], vj);
    vpart[wv][j] = vj;
    __syncthreads();
    if (wv == 0) {
        float vv = fmaxf(vpart[0][j] + vpart[1][j] + vpart[2][j] + vpart[3][j], 0.f);
        float v = wave_reduce_sum(vv * C2[j]);
        if (j == 0) {
            float m = fmaxf(fmaxf(logits[0], logits[1]), fmaxf(logits[2], logits[3]));
            float e0 = __expf(logits[0] - m), e1 = __expf(logits[1] - m);
            float e2 = __expf(logits[2] - m), e3 = __expf(logits[3] - m);
            float sum = e0 + e1 + e2 + e3;
            out[0] = e0 / sum; out[1] = e1 / sum; out[2] = e2 / sum; out[3] = e3 / sum;
            out[4] = v + bc2[0];
        }
    }
    out[5 + wv * 64 + j] = zc[wv][j];
}

extern "C" void kernel_launch(void* const* d_in, const int* in_sizes, int n_in,
                              void* d_out, int out_size, void* d_ws, size_t ws_size,
                              hipStream_t stream) {
    const float* x    = (const float*)d_in[0];
    const int*   ei   = (const int*)d_in[1];
    const float* ea   = (const float*)d_in[2];
    const int*   asg  = (const int*)d_in[3];
    const float* W1   = (const float*)d_in[4];
    const float* as1  = (const float*)d_in[5];
    const float* ad1  = (const float*)d_in[6];
    const float* We1  = (const float*)d_in[7];
    const float* ae1  = (const float*)d_in[8];
    const float* b1   = (const float*)d_in[9];
    const float* W2   = (const float*)d_in[10];
    const float* as2  = (const float*)d_in[11];
    const float* ad2  = (const float*)d_in[12];
    const float* We2  = (const float*)d_in[13];
    const float* ae2  = (const float*)d_in[14];
    const float* b2   = (const float*)d_in[15];
    const float* A1   = (const float*)d_in[16];
    const float* ba1  = (const float*)d_in[17];
    const float* A2   = (const float*)d_in[18];
    const float* ba2  = (const float*)d_in[19];
    const float* C1   = (const float*)d_in[20];
    const float* bc1  = (const float*)d_in[21];
    const float* C2   = (const float*)d_in[22];
    const float* bc2  = (const float*)d_in[23];
    const int* src = ei;
    const int* dst = ei + NE;

    char* w = (char*)d_ws;
    size_t off = 0;
    auto alloc = [&](size_t bytes) -> void* {
        void* p = w + off;
        off += (bytes + 255) & ~(size_t)255;
        return p;
    };
    // contiguous zero-init region: hist | cs | z1 | gacc
    int*   hist   = (int*)alloc(NN * sizeof(int));
    float* cs     = (float*)alloc(NN * 4 * sizeof(float));
    float* z1     = (float*)alloc(NN * sizeof(float));
    float* gacc   = (float*)alloc(264 * sizeof(float));
    size_t zspan  = (size_t)((char*)gacc + 264 * sizeof(float) - (char*)hist);
    float* a_src1 = (float*)alloc(NN * 4 * sizeof(float));
    float* a_dst1 = (float*)alloc(NN * 4 * sizeof(float));
    float* a_src2 = (float*)alloc(NN * sizeof(float));
    float* a_dst2 = (float*)alloc(NN * sizeof(float));
    uint4* xpack  = (uint4*)alloc(NN * sizeof(uint4));
    int*   offs   = (int*)alloc((NN + 1) * sizeof(int));
    int*   cursor = (int*)alloc(NN * sizeof(int));
    int*   bsum   = (int*)alloc(128 * sizeof(int));
    int*   bexcl  = (int*)alloc(128 * sizeof(int));
    int4*  es2    = (int4*)alloc(NE * sizeof(int4));
    int2*  einf   = (int2*)alloc(NE * sizeof(int2));
    float* ewv    = (float*)alloc(NE * sizeof(float));
    unsigned short* xh2b = (unsigned short*)alloc(NN * 64 * sizeof(unsigned short));
    unsigned short* W2fr = (unsigned short*)alloc(16384 * sizeof(unsigned short));
    float* cb     = (float*)alloc(64 * sizeof(float));
    (void)ws_size; (void)n_in; (void)in_sizes; (void)out_size;

    hipMemsetAsync(hist, 0, zspan, stream);

    k_pre<<<65, 256, 0, stream>>>(W1, as1, ad1, We1, ae1, We2, ae2, W2, cb, W2fr);
    k_node1h<<<(NN + 255) / 256, 256, 0, stream>>>(x, cb, dst, a_src1, a_dst1, xpack, hist);
    k_scanA<<<98, 1024, 0, stream>>>(hist, bsum);
    k_scanB<<<1, 128, 0, stream>>>(bsum, bexcl);
    k_scanC<<<98, 1024, 0, stream>>>(hist, bexcl, offs, cursor);
    k_scatter<<<(NE + 255) / 256, 256, 0, stream>>>(src, dst, ea, a_src1, a_dst1, cb,
                                                    cursor, es2);
    k_conv1red<<<NN / 32, 256, 0, stream>>>(xpack, W1, b1, offs, es2,
                                            as2, ad2, W2fr, asg, xh2b, a_src2, a_dst2, einf);
    k_zA<<<(NE + 255) / 256, 256, 0, stream>>>(es2, einf, a_src2, a_dst2, cb, ewv, z1);
    k_zB<<<(NE + 255) / 256, 256, 0, stream>>>(einf, ewv, z1, cs);
    k_pool<<<NPB, 256, 0, stream>>>(xh2b, cs, asg, x, gacc);
    k_head<<<1, 256, 0, stream>>>(gacc, b2, A1, ba1, A2, ba2, C1, bc1, C2, bc2, (float*)d_out);
}

// Round 12
// 210.158 us; speedup vs baseline: 1.2392x; 1.2392x over previous
//
#include <hip/hip_runtime.h>

#define NN 100000
#define NE 800000
#define NPB 512   // k_pool blocks
#define SRCMASK 0x01FFFFFF

typedef short bf16x8 __attribute__((ext_vector_type(8)));
typedef float f32x4 __attribute__((ext_vector_type(4)));

__device__ __forceinline__ float wave_reduce_sum(float v) {
    #pragma unroll
    for (int o = 32; o > 0; o >>= 1) v += __shfl_down(v, o, 64);
    return v; // valid in lane 0
}

__device__ __forceinline__ unsigned short f2bf(float f) {
    unsigned u = __float_as_uint(f);
    unsigned r = (u + 0x7FFFu + ((u >> 16) & 1u)) >> 16;
    return (unsigned short)r;
}
__device__ __forceinline__ float bf2f(unsigned short b) {
    return __uint_as_float(((unsigned)b) << 16);
}
__device__ __forceinline__ float bflo(unsigned u) {   // low bf16 of u32
    return __uint_as_float(u << 16);
}
__device__ __forceinline__ float bfhi(unsigned u) {   // high bf16 of u32
    return __uint_as_float(u & 0xFFFF0000u);
}

// cb layout (floats): [0..27] vs1(k*4+h)  [28..55] vd1  [56..59] c1[h]  [60] c2
// W2fr: 5 col-tiles x 8 k-slices, B-fragment order; tile ct=4 col0=W2@as2, col1=W2@ad2
__global__ void k_pre(const float* __restrict__ W1, const float* __restrict__ as1,
                      const float* __restrict__ ad1,
                      const float* __restrict__ We1, const float* __restrict__ ae1,
                      const float* __restrict__ We2, const float* __restrict__ ae2,
                      const float* __restrict__ W2, const float* __restrict__ as2,
                      const float* __restrict__ ad2,
                      float* __restrict__ cb, unsigned short* __restrict__ W2fr) {
    int t = threadIdx.x;
    if (blockIdx.x == 0) {
        if (t < 28) {
            int k = t >> 2, h = t & 3;
            float s = 0.f, d = 0.f;
            for (int c = 0; c < 64; ++c) {
                float w = W1[k * 256 + h * 64 + c];
                s += w * as1[h * 64 + c];
                d += w * ad1[h * 64 + c];
            }
            cb[t] = s; cb[28 + t] = d;
        } else if (t < 32) {
            int h = t - 28;
            float s = 0.f;
            for (int c = 0; c < 64; ++c) s += We1[h * 64 + c] * ae1[h * 64 + c];
            cb[56 + h] = s;
        } else if (t == 32) {
            float s = 0.f;
            for (int c = 0; c < 64; ++c) s += We2[c] * ae2[c];
            cb[60] = s;
        }
    } else {
        int o = (blockIdx.x - 1) * 256 + t;        // 0..20479
        if (o >= 20480) return;
        int i = o & 7, l = (o >> 3) & 63, rest = o >> 9;
        int ct = rest % 5, ks = rest / 5;
        int k = ks * 32 + ((l >> 4) * 8) + i;
        int cl = l & 15;
        if (ct < 4) {
            W2fr[o] = f2bf(W2[k * 64 + ct * 16 + cl]);
        } else if (cl < 2) {
            const float* av = (cl == 0) ? as2 : ad2;
            float s = 0.f;
            for (int j = 0; j < 64; ++j) s += W2[k * 64 + j] * av[j];
            W2fr[o] = f2bf(s);
        } else {
            W2fr[o] = 0;
        }
    }
}

// per-node: conv1 attention coefficients + packed bf16 x-record; fused dst histogram
__global__ void k_node1h(const float* __restrict__ x, const float* __restrict__ cb,
                         const int* __restrict__ dst,
                         float* __restrict__ a_src1, float* __restrict__ a_dst1,
                         uint4* __restrict__ xpack, int* __restrict__ hist) {
    int n = blockIdx.x * 256 + threadIdx.x;
    if (n >= NN) return;
    float xv[7];
    #pragma unroll
    for (int k = 0; k < 7; ++k) xv[k] = x[n * 7 + k];
    float s[4] = {0.f, 0.f, 0.f, 0.f}, d[4] = {0.f, 0.f, 0.f, 0.f};
    #pragma unroll
    for (int k = 0; k < 7; ++k)
        #pragma unroll
        for (int h = 0; h < 4; ++h) {
            s[h] += xv[k] * cb[k * 4 + h];
            d[h] += xv[k] * cb[28 + k * 4 + h];
        }
    *(float4*)(a_src1 + n * 4) = make_float4(s[0], s[1], s[2], s[3]);
    *(float4*)(a_dst1 + n * 4) = make_float4(d[0], d[1], d[2], d[3]);
    unsigned p0 = (unsigned)f2bf(xv[0]) | ((unsigned)f2bf(xv[1]) << 16);
    unsigned p1 = (unsigned)f2bf(xv[2]) | ((unsigned)f2bf(xv[3]) << 16);
    unsigned p2 = (unsigned)f2bf(xv[4]) | ((unsigned)f2bf(xv[5]) << 16);
    unsigned p3 = (unsigned)f2bf(xv[6]) | ((unsigned)f2bf(1.f) << 16);
    xpack[n] = make_uint4(p0, p1, p2, p3);
    // histogram: edges [n*8, n*8+8)
    int e0 = n * 8;
    int4 d0 = *(const int4*)(dst + e0);
    int4 d1 = *(const int4*)(dst + e0 + 4);
    atomicAdd(&hist[d0.x], 1); atomicAdd(&hist[d0.y], 1);
    atomicAdd(&hist[d0.z], 1); atomicAdd(&hist[d0.w], 1);
    atomicAdd(&hist[d1.x], 1); atomicAdd(&hist[d1.y], 1);
    atomicAdd(&hist[d1.z], 1); atomicAdd(&hist[d1.w], 1);
}

// --- 3-phase parallel exclusive scan over hist[NN] -> offs[NN+1], cursor[NN] ---
__global__ __launch_bounds__(1024) void k_scanA(const int* __restrict__ hist,
                                                int* __restrict__ bsum) {
    __shared__ int ws[16];
    int i = blockIdx.x * 1024 + threadIdx.x;
    int lane = threadIdx.x & 63, wid = threadIdx.x >> 6;
    int v = (i < NN) ? hist[i] : 0;
    #pragma unroll
    for (int o = 32; o; o >>= 1) v += __shfl_down(v, o, 64);
    if (lane == 0) ws[wid] = v;
    __syncthreads();
    if (wid == 0) {
        int u = (lane < 16) ? ws[lane] : 0;
        #pragma unroll
        for (int o = 8; o; o >>= 1) u += __shfl_down(u, o, 64);
        if (lane == 0) bsum[blockIdx.x] = u;
    }
}

__global__ void k_scanB(const int* __restrict__ bsum, int* __restrict__ bexcl) {
    __shared__ int w0tot;
    int t = threadIdx.x, lane = t & 63, wid = t >> 6;
    int v = (t < 98) ? bsum[t] : 0;
    int s = v;
    #pragma unroll
    for (int d = 1; d < 64; d <<= 1) { int u = __shfl_up(s, d, 64); if (lane >= d) s += u; }
    if (t == 63) w0tot = s;
    __syncthreads();
    if (wid == 1) s += w0tot;
    if (t < 98) bexcl[t] = s - v;
}

__global__ __launch_bounds__(1024) void k_scanC(const int* __restrict__ hist,
                                                const int* __restrict__ bexcl,
                                                int* __restrict__ offs,
                                                int* __restrict__ cursor) {
    __shared__ int ws[16];
    int b = blockIdx.x;
    int i = b * 1024 + threadIdx.x;
    int lane = threadIdx.x & 63, wid = threadIdx.x >> 6;
    int v = (i < NN) ? hist[i] : 0;
    int s = v;
    #pragma unroll
    for (int d = 1; d < 64; d <<= 1) { int u = __shfl_up(s, d, 64); if (lane >= d) s += u; }
    if (lane == 63) ws[wid] = s;
    __syncthreads();
    if (wid == 0) {
        int u2 = (lane < 16) ? ws[lane] : 0;
        #pragma unroll
        for (int d = 1; d < 16; d <<= 1) { int uu = __shfl_up(u2, d, 64); if (lane >= d) u2 += uu; }
        if (lane < 16) ws[lane] = u2;
    }
    __syncthreads();
    int incl = s + (wid ? ws[wid - 1] : 0) + bexcl[b];
    if (i < NN) { offs[i + 1] = incl; cursor[i] = incl - v; }
    if (i == 0) offs[0] = 0;
}

// scatter + conv1 edge weights: es2[pos] = {w01, w23 (bf16x4), src|(dst&31)<<25, ea}
__global__ void k_scatter(const int* __restrict__ src, const int* __restrict__ dst,
                          const float* __restrict__ ea,
                          const float* __restrict__ a_src1, const float* __restrict__ a_dst1,
                          const float* __restrict__ cb,
                          int* __restrict__ cursor, int4* __restrict__ es2) {
    int e = blockIdx.x * 256 + threadIdx.x;
    if (e >= NE) return;
    int s = src[e], d = dst[e];
    float eav = ea[e];
    int pos = atomicAdd(&cursor[d], 1);
    float4 as_ = *(const float4*)(a_src1 + s * 4);
    float4 ad_ = *(const float4*)(a_dst1 + d * 4);
    float lg0 = as_.x + ad_.x + eav * cb[56];
    float lg1 = as_.y + ad_.y + eav * cb[57];
    float lg2 = as_.z + ad_.z + eav * cb[58];
    float lg3 = as_.w + ad_.w + eav * cb[59];
    lg0 = lg0 >= 0.f ? lg0 : 0.2f * lg0;
    lg1 = lg1 >= 0.f ? lg1 : 0.2f * lg1;
    lg2 = lg2 >= 0.f ? lg2 : 0.2f * lg2;
    lg3 = lg3 >= 0.f ? lg3 : 0.2f * lg3;
    unsigned w01 = (unsigned)f2bf(__expf(lg0)) | ((unsigned)f2bf(__expf(lg1)) << 16);
    unsigned w23 = (unsigned)f2bf(__expf(lg2)) | ((unsigned)f2bf(__expf(lg3)) << 16);
    es2[pos] = make_int4((int)w01, (int)w23, s | ((d & 31) << 25), __float_as_int(eav));
}

// fused conv1: packed-LDS two-phase segmented reduce -> h -> MFMA
// 5th col-tile computes a_src2/a_dst2 directly (no shfl epilogue)
__global__ __launch_bounds__(256, 7) void k_conv1red(
    const uint4* __restrict__ xpack, const float* __restrict__ W1, const float* __restrict__ b1,
    const int* __restrict__ offs, const int4* __restrict__ es2,
    const unsigned short* __restrict__ W2fr,
    unsigned short* __restrict__ xh2b, float* __restrict__ a_src2, float* __restrict__ a_dst2) {
    // overlay: xs/wsx (phases 1-2) share storage with hs (finish/MFMA phases)
    __shared__ __attribute__((aligned(16))) unsigned char smem[16896];
    uint4* xs = (uint4*)smem;                                   // [256] 4096 B
    uint2* wsx = (uint2*)(smem + 4096);                         // [256] 2048 B
    typedef unsigned short hsrow[264];
    hsrow* hs = (hsrow*)smem;                                   // [32][264] 16896 B
    __shared__ int soffs[33];
    __shared__ float ms[32][33];
    int t = threadIdx.x, lane = t & 63, wid = t >> 6;
    int n0 = blockIdx.x * 32;
    if (t <= 32) soffs[t] = offs[n0 + t];
    float w1r[7][4], b1r[4];
    #pragma unroll
    for (int k = 0; k < 7; ++k)
        #pragma unroll
        for (int h = 0; h < 4; ++h) w1r[k][h] = W1[k * 256 + h * 64 + lane];
    #pragma unroll
    for (int h = 0; h < 4; ++h) b1r[h] = b1[h * 64 + lane];
    __syncthreads();
    int E0 = soffs[0], E1 = soffs[32];
    int g = t >> 3, q = t & 7;
    int go0 = soffs[g], go1 = soffs[g + 1];
    int qh = q >> 1;
    int xsl = (q & 1) ? 0 : 16;    // shift to put selected bf16 in high half
    float mh0 = 0.f, mh1 = 0.f, mh2 = 0.f, mh3 = 0.f;
    for (int C0 = E0; C0 < E1; C0 += 256) {
        int C1 = min(C0 + 256, E1);
        int j = C0 + t;
        if (j < C1) {
            int4 e4 = es2[j];
            xs[t] = xpack[e4.z & SRCMASK];
            wsx[t] = make_uint2((unsigned)e4.x, (unsigned)e4.y);
        }
        __syncthreads();
        int lo = max(go0, C0) - C0, hi = min(go1, C1) - C0;
        for (int jj = lo; jj < hi; ++jj) {
            unsigned xu = ((const unsigned*)&xs[jj])[qh];
            float xv = __uint_as_float((xu << xsl) & 0xFFFF0000u);
            uint2 wv = wsx[jj];
            mh0 = fmaf(bflo(wv.x), xv, mh0);
            mh1 = fmaf(bfhi(wv.x), xv, mh1);
            mh2 = fmaf(bflo(wv.y), xv, mh2);
            mh3 = fmaf(bfhi(wv.y), xv, mh3);
        }
        __syncthreads();
    }
    ms[g][0 * 8 + q] = mh0; ms[g][1 * 8 + q] = mh1;
    ms[g][2 * 8 + q] = mh2; ms[g][3 * 8 + q] = mh3;
    __syncthreads();          // xs/wsx dead from here; hs may now overwrite
    // finish: 8 nodes per wave, lane = channel
    for (int gi = wid * 8; gi < wid * 8 + 8; ++gi) {
        bool has = soffs[gi + 1] > soffs[gi];
        #pragma unroll
        for (int h = 0; h < 4; ++h) {
            float rz = __builtin_amdgcn_rcpf(ms[gi][h * 8 + 7]);
            float a = 0.f;
            #pragma unroll
            for (int k = 0; k < 7; ++k) a = fmaf(ms[gi][h * 8 + k], w1r[k][h], a);
            float mm = (has ? a * rz : 0.f) + b1r[h];
            float hv = mm > 0.f ? mm : (__expf(mm) - 1.f);
            hs[gi][h * 64 + lane] = f2bf(hv);
        }
    }
    __syncthreads();
    // MFMA: 2 node-tiles x 5 col-tiles (ct=4 -> a_src2/a_dst2 columns)
    int row = lane & 15, kg = lane >> 4;
    #pragma unroll
    for (int u = wid; u < 10; u += 4) {
        int nt = u & 1, ct = u >> 1;
        f32x4 acc = {0.f, 0.f, 0.f, 0.f};
        #pragma unroll
        for (int ks = 0; ks < 8; ++ks) {
            bf16x8 av = *(const bf16x8*)&hs[nt * 16 + row][ks * 32 + kg * 8];
            bf16x8 bv = *(const bf16x8*)(W2fr + (((ks * 5 + ct) * 64) + lane) * 8);
            acc = __builtin_amdgcn_mfma_f32_16x16x32_bf16(av, bv, acc, 0, 0, 0);
        }
        if (ct < 4) {
            #pragma unroll
            for (int i = 0; i < 4; ++i)
                xh2b[(n0 + nt * 16 + kg * 4 + i) * 64 + ct * 16 + row] = f2bf(acc[i]);
        } else if (row == 0) {
            #pragma unroll
            for (int i = 0; i < 4; ++i) a_src2[n0 + nt * 16 + kg * 4 + i] = acc[i];
        } else if (row == 1) {
            #pragma unroll
            for (int i = 0; i < 4; ++i) a_dst2[n0 + nt * 16 + kg * 4 + i] = acc[i];
        }
    }
}

// conv2 normalization: single-gather two-phase over sorted runs.
// pass 1 (edge-parallel per chunk): ew = exp(leaky(logit)) -> LDS (+ ewv if multi-chunk)
// z summed per node from LDS; pass 2 (edge-parallel): cs[src][cluster(dst)] += ew*rz
__global__ __launch_bounds__(256) void k_znorm(
    const int4* __restrict__ es2, const int* __restrict__ offs,
    const float* __restrict__ a_src2, const float* __restrict__ a_dst2,
    const int* __restrict__ assign, const float* __restrict__ cb,
    float* __restrict__ ewv, float* __restrict__ cs) {
    __shared__ int soffs[33];
    __shared__ float adL[32];
    __shared__ int asgL[32];
    __shared__ float ewL[256];
    __shared__ float rzL[32];
    int t = threadIdx.x;
    int n0 = blockIdx.x * 32;
    if (t <= 32) soffs[t] = offs[n0 + t];
    if (t < 32) { adL[t] = a_dst2[n0 + t]; asgL[t] = assign[n0 + t]; }
    __syncthreads();
    int E0 = soffs[0], E1 = soffs[32];
    bool single = (E1 - E0) <= 256;
    int g = t >> 3, q = t & 7;
    int go0 = soffs[g], go1 = soffs[g + 1];
    float c2 = cb[60];
    float z = 0.f;
    for (int C0 = E0; C0 < E1; C0 += 256) {
        int C1 = min(C0 + 256, E1);
        int j = C0 + t;
        if (j < C1) {
            int4 e4 = es2[j];
            int sx = e4.z & SRCMASK;
            int d5 = (e4.z >> 25) & 31;
            float lg = a_src2[sx] + adL[d5] + __int_as_float(e4.w) * c2;
            lg = lg >= 0.f ? lg : 0.2f * lg;
            float ew = __expf(lg);
            ewL[t] = ew;
            if (!single) ewv[j] = ew;
        }
        __syncthreads();
        int lo = max(go0, C0) - C0, hi = min(go1, C1) - C0;
        for (int jj = lo + q; jj < hi; jj += 8) z += ewL[jj];
        if (!single) __syncthreads();
    }
    z += __shfl_xor(z, 1, 64);
    z += __shfl_xor(z, 2, 64);
    z += __shfl_xor(z, 4, 64);
    if (q == 0) rzL[g] = __builtin_amdgcn_rcpf(z);
    __syncthreads();
    // pass 2: edge-parallel cs atomics
    for (int C0 = E0; C0 < E1; C0 += 256) {
        int C1 = min(C0 + 256, E1);
        int j = C0 + t;
        if (j < C1) {
            int4 e4 = es2[j];
            int sx = e4.z & SRCMASK;
            int d5 = (e4.z >> 25) & 31;
            float ew = single ? ewL[t] : ewv[j];
            atomicAdd(&cs[sx * 4 + asgL[d5]], ew * rzL[d5]);
        }
    }
}

// pooling as tiny GEMM: 8 lanes/node, 16B loads, register accumulators, direct gacc atomics
__global__ __launch_bounds__(256) void k_pool(
    const unsigned short* __restrict__ xh2b, const float* __restrict__ cs,
    const int* __restrict__ assign, const float* __restrict__ x,
    float* __restrict__ gacc) {
    __shared__ float csum[264];
    int t = threadIdx.x;
    int q = t & 7, slot = t >> 3;             // 32 node-slots per block
    float a0[8], a1[8], a2[8], a3[8];
    #pragma unroll
    for (int j = 0; j < 8; ++j) { a0[j] = 0.f; a1[j] = 0.f; a2[j] = 0.f; a3[j] = 0.f; }
    float cnt0 = 0.f, cnt1 = 0.f, cnt2 = 0.f, cnt3 = 0.f;
    float cf0 = 0.f, cf1 = 0.f, cf2 = 0.f, cf3 = 0.f;
    for (int n = blockIdx.x * 32 + slot; n < NN; n += NPB * 32) {
        uint4 u = *(const uint4*)(xh2b + n * 64 + q * 8);
        float4 c4 = *(const float4*)(cs + n * 4);
        float xv[8];
        xv[0] = bf2f((unsigned short)u.x); xv[1] = bf2f((unsigned short)(u.x >> 16));
        xv[2] = bf2f((unsigned short)u.y); xv[3] = bf2f((unsigned short)(u.y >> 16));
        xv[4] = bf2f((unsigned short)u.z); xv[5] = bf2f((unsigned short)(u.z >> 16));
        xv[6] = bf2f((unsigned short)u.w); xv[7] = bf2f((unsigned short)(u.w >> 16));
        #pragma unroll
        for (int j = 0; j < 8; ++j) {
            a0[j] = fmaf(c4.x, xv[j], a0[j]);
            a1[j] = fmaf(c4.y, xv[j], a1[j]);
            a2[j] = fmaf(c4.z, xv[j], a2[j]);
            a3[j] = fmaf(c4.w, xv[j], a3[j]);
        }
        if (q == 0) {
            int a = assign[n];
            float xf = x[n * 7 + 6];
            cnt0 += (a == 0) ? 1.f : 0.f;  cf0 += (a == 0) ? xf : 0.f;
            cnt1 += (a == 1) ? 1.f : 0.f;  cf1 += (a == 1) ? xf : 0.f;
            cnt2 += (a == 2) ? 1.f : 0.f;  cf2 += (a == 2) ? xf : 0.f;
            cnt3 += (a == 3) ? 1.f : 0.f;  cf3 += (a == 3) ? xf : 0.f;
        }
    }
    for (int i = t; i < 264; i += 256) csum[i] = 0.f;
    __syncthreads();
    int base = q * 8;
    #pragma unroll
    for (int j = 0; j < 8; ++j) {
        atomicAdd(&csum[0 * 64 + base + j], a0[j]);
        atomicAdd(&csum[1 * 64 + base + j], a1[j]);
        atomicAdd(&csum[2 * 64 + base + j], a2[j]);
        atomicAdd(&csum[3 * 64 + base + j], a3[j]);
    }
    if (q == 0) {
        atomicAdd(&csum[256], cnt0); atomicAdd(&csum[257], cnt1);
        atomicAdd(&csum[258], cnt2); atomicAdd(&csum[259], cnt3);
        atomicAdd(&csum[260], cf0);  atomicAdd(&csum[261], cf1);
        atomicAdd(&csum[262], cf2);  atomicAdd(&csum[263], cf3);
    }
    __syncthreads();
    for (int i = t; i < 264; i += 256) atomicAdd(&gacc[i], csum[i]);
}

// final head (256 threads): cluster means (+cnt*b2), actor MLP + softmax, critic MLP
__global__ __launch_bounds__(256) void k_head(
    const float* __restrict__ gacc, const float* __restrict__ b2,
    const float* __restrict__ A1, const float* __restrict__ ba1,
    const float* __restrict__ A2, const float* __restrict__ ba2,
    const float* __restrict__ C1, const float* __restrict__ bc1,
    const float* __restrict__ C2, const float* __restrict__ bc2,
    float* __restrict__ out) {
    __shared__ float zc[4][64];
    __shared__ float cfs[4];
    __shared__ float logits[4];
    __shared__ float vpart[4][64];
    int t = threadIdx.x;
    int j = t & 63, wv = t >> 6;   // wave wv handles cluster wv
    float cnt = gacc[256 + wv];
    float den = fmaxf(cnt, 1.f);
    zc[wv][j] = (cnt > 0.f) ? (gacc[wv * 64 + j] + cnt * b2[j]) / den : 0.f;
    if (t < 4) {
        float cc = gacc[256 + t];
        cfs[t] = (cc > 0.f) ? gacc[260 + t] / fmaxf(cc, 1.f) : 0.f;
    }
    __syncthreads();
    // actor: cluster wv
    float tv = ba1[j];
    for (int k = 0; k < 64; ++k) tv = fmaf(zc[wv][k], A1[k * 64 + j], tv);
    tv = fmaf(cfs[wv], A1[64 * 64 + j], tv);
    tv = fmaxf(tv, 0.f);
    float sred = wave_reduce_sum(tv * A2[j]);
    if (j == 0) logits[wv] = sred + ba2[0];
    // critic partials: wave wv covers k in [wv*64, (wv+1)*64)
    float vj = (wv == 0) ? bc1[j] : 0.f;
    for (int kk = 0; kk < 64; ++kk) vj = fmaf(zc[wv][kk], C1[(wv * 64 + kk) * 64 + j], vj);
    vpart[wv][j] = vj;
    __syncthreads();
    if (wv == 0) {
        float vv = fmaxf(vpart[0][j] + vpart[1][j] + vpart[2][j] + vpart[3][j], 0.f);
        float v = wave_reduce_sum(vv * C2[j]);
        if (j == 0) {
            float m = fmaxf(fmaxf(logits[0], logits[1]), fmaxf(logits[2], logits[3]));
            float e0 = __expf(logits[0] - m), e1 = __expf(logits[1] - m);
            float e2 = __expf(logits[2] - m), e3 = __expf(logits[3] - m);
            float sum = e0 + e1 + e2 + e3;
            out[0] = e0 / sum; out[1] = e1 / sum; out[2] = e2 / sum; out[3] = e3 / sum;
            out[4] = v + bc2[0];
        }
    }
    out[5 + wv * 64 + j] = zc[wv][j];
}

extern "C" void kernel_launch(void* const* d_in, const int* in_sizes, int n_in,
                              void* d_out, int out_size, void* d_ws, size_t ws_size,
                              hipStream_t stream) {
    const float* x    = (const float*)d_in[0];
    const int*   ei   = (const int*)d_in[1];
    const float* ea   = (const float*)d_in[2];
    const int*   asg  = (const int*)d_in[3];
    const float* W1   = (const float*)d_in[4];
    const float* as1  = (const float*)d_in[5];
    const float* ad1  = (const float*)d_in[6];
    const float* We1  = (const float*)d_in[7];
    const float* ae1  = (const float*)d_in[8];
    const float* b1   = (const float*)d_in[9];
    const float* W2   = (const float*)d_in[10];
    const float* as2  = (const float*)d_in[11];
    const float* ad2  = (const float*)d_in[12];
    const float* We2  = (const float*)d_in[13];
    const float* ae2  = (const float*)d_in[14];
    const float* b2   = (const float*)d_in[15];
    const float* A1   = (const float*)d_in[16];
    const float* ba1  = (const float*)d_in[17];
    const float* A2   = (const float*)d_in[18];
    const float* ba2  = (const float*)d_in[19];
    const float* C1   = (const float*)d_in[20];
    const float* bc1  = (const float*)d_in[21];
    const float* C2   = (const float*)d_in[22];
    const float* bc2  = (const float*)d_in[23];
    const int* src = ei;
    const int* dst = ei + NE;

    char* w = (char*)d_ws;
    size_t off = 0;
    auto alloc = [&](size_t bytes) -> void* {
        void* p = w + off;
        off += (bytes + 255) & ~(size_t)255;
        return p;
    };
    // contiguous zero-init region: hist | cs | gacc
    int*   hist   = (int*)alloc(NN * sizeof(int));
    float* cs     = (float*)alloc(NN * 4 * sizeof(float));
    float* gacc   = (float*)alloc(264 * sizeof(float));
    size_t zspan  = (size_t)((char*)gacc + 264 * sizeof(float) - (char*)hist);
    float* a_src1 = (float*)alloc(NN * 4 * sizeof(float));
    float* a_dst1 = (float*)alloc(NN * 4 * sizeof(float));
    float* a_src2 = (float*)alloc(NN * sizeof(float));
    float* a_dst2 = (float*)alloc(NN * sizeof(float));
    uint4* xpack  = (uint4*)alloc(NN * sizeof(uint4));
    int*   offs   = (int*)alloc((NN + 1) * sizeof(int));
    int*   cursor = (int*)alloc(NN * sizeof(int));
    int*   bsum   = (int*)alloc(128 * sizeof(int));
    int*   bexcl  = (int*)alloc(128 * sizeof(int));
    int4*  es2    = (int4*)alloc(NE * sizeof(int4));
    float* ewv    = (float*)alloc(NE * sizeof(float));
    unsigned short* xh2b = (unsigned short*)alloc(NN * 64 * sizeof(unsigned short));
    unsigned short* W2fr = (unsigned short*)alloc(20480 * sizeof(unsigned short));
    float* cb     = (float*)alloc(64 * sizeof(float));
    (void)ws_size; (void)n_in; (void)in_sizes; (void)out_size;

    hipMemsetAsync(hist, 0, zspan, stream);

    k_pre<<<81, 256, 0, stream>>>(W1, as1, ad1, We1, ae1, We2, ae2, W2, as2, ad2, cb, W2fr);
    k_node1h<<<(NN + 255) / 256, 256, 0, stream>>>(x, cb, dst, a_src1, a_dst1, xpack, hist);
    k_scanA<<<98, 1024, 0, stream>>>(hist, bsum);
    k_scanB<<<1, 128, 0, stream>>>(bsum, bexcl);
    k_scanC<<<98, 1024, 0, stream>>>(hist, bexcl, offs, cursor);
    k_scatter<<<(NE + 255) / 256, 256, 0, stream>>>(src, dst, ea, a_src1, a_dst1, cb,
                                                    cursor, es2);
    k_conv1red<<<NN / 32, 256, 0, stream>>>(xpack, W1, b1, offs, es2,
                                            W2fr, xh2b, a_src2, a_dst2);
    k_znorm<<<NN / 32, 256, 0, stream>>>(es2, offs, a_src2, a_dst2, asg, cb, ewv, cs);
    k_pool<<<NPB, 256, 0, stream>>>(xh2b, cs, asg, x, gacc);
    k_head<<<1, 256, 0, stream>>>(gacc, b2, A1, ba1, A2, ba2, C1, bc1, C2, bc2, (float*)d_out);
}